// Round 7
// baseline (394.713 us; speedup 1.0000x reference)
//
#include <hip/hip_runtime.h>
#include <hip/hip_bf16.h>

typedef __bf16 bf16_t;
typedef __bf16 bf16x8 __attribute__((ext_vector_type(8)));
typedef float f32x4 __attribute__((ext_vector_type(4)));
typedef unsigned int uint;

#define T_TOK 4096
#define H_DIM 7168
#define QLORA 1536
#define KVLORA 512
#define ROPE_D 64
#define NOPE_D 128
#define NHEAD 16
#define NQKV 2112   /* QLORA + KVLORA + ROPE */
#define NQB  3072   /* NHEAD * 192 */
#define EPS_F 1e-6f

// ---------------- elementwise helpers ----------------

__global__ void cast_f32_bf16(const float* __restrict__ in, bf16_t* __restrict__ out, long n8)
{
    long stride = (long)gridDim.x * blockDim.x;
    for (long i = (long)blockIdx.x * blockDim.x + threadIdx.x; i < n8; i += stride) {
        const float4 a = ((const float4*)in)[i * 2];
        const float4 b = ((const float4*)in)[i * 2 + 1];
        bf16x8 v;
        v[0] = (bf16_t)a.x; v[1] = (bf16_t)a.y; v[2] = (bf16_t)a.z; v[3] = (bf16_t)a.w;
        v[4] = (bf16_t)b.x; v[5] = (bf16_t)b.y; v[6] = (bf16_t)b.z; v[7] = (bf16_t)b.w;
        ((bf16x8*)out)[i] = v;
    }
}

// out[C][R] (bf16) = transpose of in[R][C] (f32)
__global__ __launch_bounds__(256) void transpose_cast(const float* __restrict__ in,
                                                      bf16_t* __restrict__ out, int R, int C)
{
    __shared__ float tile[32][33];
    const int bx = blockIdx.x * 32;   // col block of in
    const int by = blockIdx.y * 32;   // row block of in
    const int tx = threadIdx.x & 31, ty = threadIdx.x >> 5;
    #pragma unroll
    for (int r = ty; r < 32; r += 8)
        tile[r][tx] = in[(long)(by + r) * C + bx + tx];
    __syncthreads();
    #pragma unroll
    for (int r = ty; r < 32; r += 8)
        out[(long)(bx + r) * R + by + tx] = (bf16_t)tile[tx][r];
}

__device__ inline float block_sum_256(float v)
{
    #pragma unroll
    for (int off = 32; off > 0; off >>= 1) v += __shfl_xor(v, off, 64);
    __shared__ float tmp[4];
    if ((threadIdx.x & 63) == 0) tmp[threadIdx.x >> 6] = v;
    __syncthreads();
    return tmp[0] + tmp[1] + tmp[2] + tmp[3];
}

// RMS-norm (qkv0 [+ qkv1])[:, :1536] -> bf16 q_a
__global__ __launch_bounds__(256) void rms_q_kernel(const float* __restrict__ qkv,
                                                    const float* __restrict__ qkvB,
                                                    const float* __restrict__ w,
                                                    bf16_t* __restrict__ q_a)
{
    const int t = blockIdx.x;
    const float* x = qkv + (long)t * NQKV;
    float loc[6];
    float ss = 0.f;
    if (qkvB) {
        const float* xB = qkvB + (long)t * NQKV;
        #pragma unroll
        for (int i = 0; i < 6; i++) {
            float v = x[threadIdx.x + 256 * i] + xB[threadIdx.x + 256 * i];
            loc[i] = v; ss += v * v;
        }
    } else {
        #pragma unroll
        for (int i = 0; i < 6; i++) {
            float v = x[threadIdx.x + 256 * i];
            loc[i] = v; ss += v * v;
        }
    }
    ss = block_sum_256(ss);
    const float sc = rsqrtf(ss / (float)QLORA + EPS_F);
    #pragma unroll
    for (int i = 0; i < 6; i++) {
        int idx = threadIdx.x + 256 * i;
        q_a[(long)t * QLORA + idx] = (bf16_t)(loc[i] * sc * w[idx]);
    }
}

// k-side: RMS-norm latent[:512] + rope latent[512:576]; write k_out, k_cache, rope_cache
__global__ __launch_bounds__(256) void k_side_kernel(const float* __restrict__ qkv,
                                                     const float* __restrict__ qkvB,
                                                     const float* __restrict__ w_kv,
                                                     const float* __restrict__ cos_sin,
                                                     const int* __restrict__ positions,
                                                     const int* __restrict__ slot_map,
                                                     float* __restrict__ k_out,
                                                     float* __restrict__ kc_out,
                                                     float* __restrict__ rc_out)
{
    const int t = blockIdx.x;
    const float* lat = qkv + (long)t * NQKV + QLORA;
    const float* latB = qkvB ? qkvB + (long)t * NQKV + QLORA : nullptr;
    float v0 = lat[threadIdx.x];
    float v1 = lat[threadIdx.x + 256];
    if (latB) { v0 += latB[threadIdx.x]; v1 += latB[threadIdx.x + 256]; }
    float ss = v0 * v0 + v1 * v1;
    ss = block_sum_256(ss);
    const float sc = rsqrtf(ss / (float)KVLORA + EPS_F);
    const int slot = slot_map[t];
    const float a0 = v0 * sc * w_kv[threadIdx.x];
    const float a1 = v1 * sc * w_kv[threadIdx.x + 256];
    k_out[(long)t * 576 + threadIdx.x]        = a0;
    k_out[(long)t * 576 + 256 + threadIdx.x]  = a1;
    kc_out[(long)slot * KVLORA + threadIdx.x]       = a0;
    kc_out[(long)slot * KVLORA + 256 + threadIdx.x] = a1;
    if (threadIdx.x < 32) {
        const int j = threadIdx.x;
        const int pos = positions[t];
        const float c = cos_sin[pos * 64 + j];
        const float s = cos_sin[pos * 64 + 32 + j];
        float x1 = lat[KVLORA + 2 * j];
        float x2 = lat[KVLORA + 2 * j + 1];
        if (latB) { x1 += latB[KVLORA + 2 * j]; x2 += latB[KVLORA + 2 * j + 1]; }
        const float o1 = x1 * c - x2 * s;
        const float o2 = x2 * c + x1 * s;
        k_out[(long)t * 576 + 512 + j]      = o1;
        k_out[(long)t * 576 + 512 + 32 + j] = o2;
        rc_out[(long)slot * 64 + j]      = o1;
        rc_out[(long)slot * 64 + 32 + j] = o2;
    }
}

// split q_b into q_nope (bf16, [h][t][128]) and roped q_pe -> q_out[..., 512:576]
__global__ __launch_bounds__(256) void split_q_kernel(const float* __restrict__ q_b,
                                                      const float* __restrict__ cos_sin,
                                                      const int* __restrict__ positions,
                                                      bf16_t* __restrict__ q_nope,
                                                      float* __restrict__ q_out)
{
    const int t = blockIdx.x;
    const float* row = q_b + (long)t * NQB;
    #pragma unroll
    for (int i = 0; i < 8; i++) {
        int idx = threadIdx.x + 256 * i;      // 0..2047
        int h = idx >> 7, n = idx & 127;
        q_nope[((long)h * T_TOK + t) * NOPE_D + n] = (bf16_t)row[h * 192 + n];
    }
    const int pos = positions[t];
    #pragma unroll
    for (int i = 0; i < 2; i++) {
        int p = threadIdx.x + 256 * i;        // 0..511
        int h = p >> 5, j = p & 31;
        const float c = cos_sin[pos * 64 + j];
        const float s = cos_sin[pos * 64 + 32 + j];
        const float x1 = row[h * 192 + 128 + 2 * j];
        const float x2 = row[h * 192 + 128 + 2 * j + 1];
        q_out[(long)t * 9216 + h * 576 + 512 + j]      = x1 * c - x2 * s;
        q_out[(long)t * 9216 + h * 576 + 512 + 32 + j] = x2 * c + x1 * s;
    }
}

// ------ 3-buffer, 2-deep-prefetch bf16 MFMA GEMM (counted vmcnt), swizzled ----
// C(MxN f32) = A(MxK bf16) * B^T(NxK bf16); M%128==0, K%128==0 (nt>=2); N clamped.
// 128x128 tile, BK=64, 8 waves (2Mx4N, wave tile 64x32, 4x2 acc).
// Pipeline: prologue stages tiles 0,1; iter t stages tile t+2 into buf (t+2)%3.
// Each stage = exactly 4 wave gload_lds -> s_waitcnt vmcnt(4) at iter top
// guarantees tile t landed while t+1 stays in flight (T4 counted vmcnt; never
// drain to 0 in-loop). ONE barrier per iter. Bank swizzle as round 5 (rule #21):
// physical col byte c of row r at c ^ ((r&7)<<4); write side pre-swizzles the
// GLOBAL col chunk; read side XORs the frag base; ks=1 = base ^ 64.
#define GBM 128
#define GBN 128
#define GBK 64
#define ABUF (GBM * GBK)          /* bf16 elems per A buffer (16 KB) */
#define BBUF (GBN * GBK)

__global__ __launch_bounds__(512) void gemm_mfma(
    const bf16_t* __restrict__ A, int lda, long sA,
    const bf16_t* __restrict__ Bt, int ldb, long sB,
    float* __restrict__ C, int ldc, long sC,
    int K, int N)
{
    __shared__ bf16_t As[3][ABUF];   // 3 x 16 KB
    __shared__ bf16_t Bs[3][BBUF];   // 3 x 16 KB   (96 KB total -> 1 block/CU)

    // bijective XCD-chunked swizzle over the x-y plane (nwg % 8 == 0 for all our grids)
    const int nwg = gridDim.x * gridDim.y;
    const int bid = blockIdx.y * gridDim.x + blockIdx.x;
    const int cpx = nwg >> 3;
    const int swz = (bid & 7) * cpx + (bid >> 3);
    const int bx = swz % gridDim.x;
    const int by = swz / gridDim.x;

    const int tid = threadIdx.x;
    const int lane = tid & 63;
    const int w = tid >> 6;            // 0..7
    const int wr = w >> 2, wc = w & 3; // 2x4 wave grid; wave tile 64x32
    const int fr = lane & 15;
    const int kg = lane >> 4;

    const long brow = (long)by * GBM;
    const long bcol = (long)bx * GBN;

    const bf16_t* Ab = A + blockIdx.z * sA + brow * lda;
    const bf16_t* Bb = Bt + blockIdx.z * sB;
    float* Cb = C + blockIdx.z * sC + brow * ldc;

    // staging geometry: wave-issue = 1 KB = 8 rows x 128B; 2 issues/wave A + 2 B = 4.
    // Global col chunk pre-swizzled so linear LDS writes realize the bank swizzle.
    const int srow = w * 16 + (lane >> 3);
    const int scol = (((lane & 7) ^ (lane >> 3)) * 8);

    // per-thread swizzled LDS fragment-read byte addresses (buffer 0, ks=0)
    const uint rd_sw = (uint)((kg * 16) ^ ((fr & 7) << 4));
    const uint a_base0 = (uint)(uintptr_t)(&As[0][0]) + (uint)((wr * 64 + fr) * 128) + rd_sw;
    const uint b_base0 = (uint)(uintptr_t)(&Bs[0][0]) + (uint)((wc * 32 + fr) * 128) + rd_sw;

    f32x4 acc[4][2] = {};

    const int nt = K / GBK;

    auto stage = [&](int buf, int k0) {
        #pragma unroll
        for (int it = 0; it < 2; it++) {
            const int r = srow + it * 8;
            __builtin_amdgcn_global_load_lds(
                (const __attribute__((address_space(1))) void*)(Ab + (long)r * lda + k0 + scol),
                (__attribute__((address_space(3))) void*)(&As[buf][(w * 16 + it * 8) * GBK]),
                16, 0, 0);
        }
        #pragma unroll
        for (int it = 0; it < 2; it++) {
            const int r = srow + it * 8;
            long bn = bcol + r; if (bn >= N) bn = N - 1;   // clamp; garbage cols masked at store
            __builtin_amdgcn_global_load_lds(
                (const __attribute__((address_space(1))) void*)(Bb + bn * ldb + k0 + scol),
                (__attribute__((address_space(3))) void*)(&Bs[buf][(w * 16 + it * 8) * GBK]),
                16, 0, 0);
        }
    };

    // prologue: stage tiles 0 and 1 (nt >= 2 for all our GEMMs)
    stage(0, 0);
    stage(1, GBK);

    int cur = 0;
    for (int t = 0; t < nt; ++t) {
        // tile t's 4 loads are the oldest; keep tile t+1's 4 in flight
        if (t + 1 < nt)
            asm volatile("s_waitcnt vmcnt(4)" ::: "memory");
        else
            asm volatile("s_waitcnt vmcnt(0)" ::: "memory");
        __builtin_amdgcn_s_barrier();   // all waves' tile-t data now in LDS

        // stage tile t+2 into buf (t+2)%3 == (t-1)%3 (safe: its readers passed
        // the barrier above after finishing iter t-1's ds_reads)
        if (t + 2 < nt) {
            int nxt = cur + 2; if (nxt >= 3) nxt -= 3;
            stage(nxt, (t + 2) * GBK);
        }

        const uint aa  = a_base0 + (uint)(cur * (ABUF * 2));
        const uint bb  = b_base0 + (uint)(cur * (BBUF * 2));
        const uint aaX = aa ^ 64u;   // ks=1: +64 col byte, XOR-compatible (kg*16 < 64)
        const uint bbX = bb ^ 64u;
        bf16x8 a00, a01, a02, a03, a10, a11, a12, a13, b00, b01, b10, b11;
        // A frags: row stride 16*128B = 2048 (row&7 invariant -> swizzle-safe immediates)
        asm volatile("ds_read_b128 %0, %1 offset:0"    : "=v"(a00) : "v"(aa));
        asm volatile("ds_read_b128 %0, %1 offset:2048" : "=v"(a01) : "v"(aa));
        asm volatile("ds_read_b128 %0, %1 offset:4096" : "=v"(a02) : "v"(aa));
        asm volatile("ds_read_b128 %0, %1 offset:6144" : "=v"(a03) : "v"(aa));
        asm volatile("ds_read_b128 %0, %1 offset:0"    : "=v"(a10) : "v"(aaX));
        asm volatile("ds_read_b128 %0, %1 offset:2048" : "=v"(a11) : "v"(aaX));
        asm volatile("ds_read_b128 %0, %1 offset:4096" : "=v"(a12) : "v"(aaX));
        asm volatile("ds_read_b128 %0, %1 offset:6144" : "=v"(a13) : "v"(aaX));
        // B frags
        asm volatile("ds_read_b128 %0, %1 offset:0"    : "=v"(b00) : "v"(bb));
        asm volatile("ds_read_b128 %0, %1 offset:2048" : "=v"(b01) : "v"(bb));
        asm volatile("ds_read_b128 %0, %1 offset:0"    : "=v"(b10) : "v"(bbX));
        asm volatile("ds_read_b128 %0, %1 offset:2048" : "=v"(b11) : "v"(bbX));
        asm volatile("s_waitcnt lgkmcnt(0)" ::: "memory");
        __builtin_amdgcn_sched_barrier(0);   // rule #18: keep MFMAs below the wait

        acc[0][0] = __builtin_amdgcn_mfma_f32_16x16x32_bf16(a00, b00, acc[0][0], 0, 0, 0);
        acc[0][1] = __builtin_amdgcn_mfma_f32_16x16x32_bf16(a00, b01, acc[0][1], 0, 0, 0);
        acc[1][0] = __builtin_amdgcn_mfma_f32_16x16x32_bf16(a01, b00, acc[1][0], 0, 0, 0);
        acc[1][1] = __builtin_amdgcn_mfma_f32_16x16x32_bf16(a01, b01, acc[1][1], 0, 0, 0);
        acc[2][0] = __builtin_amdgcn_mfma_f32_16x16x32_bf16(a02, b00, acc[2][0], 0, 0, 0);
        acc[2][1] = __builtin_amdgcn_mfma_f32_16x16x32_bf16(a02, b01, acc[2][1], 0, 0, 0);
        acc[3][0] = __builtin_amdgcn_mfma_f32_16x16x32_bf16(a03, b00, acc[3][0], 0, 0, 0);
        acc[3][1] = __builtin_amdgcn_mfma_f32_16x16x32_bf16(a03, b01, acc[3][1], 0, 0, 0);
        acc[0][0] = __builtin_amdgcn_mfma_f32_16x16x32_bf16(a10, b10, acc[0][0], 0, 0, 0);
        acc[0][1] = __builtin_amdgcn_mfma_f32_16x16x32_bf16(a10, b11, acc[0][1], 0, 0, 0);
        acc[1][0] = __builtin_amdgcn_mfma_f32_16x16x32_bf16(a11, b10, acc[1][0], 0, 0, 0);
        acc[1][1] = __builtin_amdgcn_mfma_f32_16x16x32_bf16(a11, b11, acc[1][1], 0, 0, 0);
        acc[2][0] = __builtin_amdgcn_mfma_f32_16x16x32_bf16(a12, b10, acc[2][0], 0, 0, 0);
        acc[2][1] = __builtin_amdgcn_mfma_f32_16x16x32_bf16(a12, b11, acc[2][1], 0, 0, 0);
        acc[3][0] = __builtin_amdgcn_mfma_f32_16x16x32_bf16(a13, b10, acc[3][0], 0, 0, 0);
        acc[3][1] = __builtin_amdgcn_mfma_f32_16x16x32_bf16(a13, b11, acc[3][1], 0, 0, 0);

        cur = (cur + 1 == 3) ? 0 : cur + 1;
    }

    // C/D layout: col = lane&15, row = (lane>>4)*4 + reg
    #pragma unroll
    for (int i = 0; i < 4; i++) {
        #pragma unroll
        for (int j = 0; j < 2; j++) {
            const int row0 = wr * 64 + i * 16 + kg * 4;
            const long col = bcol + wc * 32 + j * 16 + fr;
            if (col < N) {
                #pragma unroll
                for (int r = 0; r < 4; r++)
                    Cb[(long)(row0 + r) * ldc + col] = acc[i][j][r];
            }
        }
    }
}

// ---------------- launcher ----------------

extern "C" void kernel_launch(void* const* d_in, const int* in_sizes, int n_in,
                              void* d_out, int out_size, void* d_ws, size_t ws_size,
                              hipStream_t stream)
{
    const float* hs       = (const float*)d_in[0];
    const int*   positions= (const int*)d_in[1];
    const float* w_qkv_a  = (const float*)d_in[2];
    const float* q_a_ln_w = (const float*)d_in[3];
    const float* w_q_b    = (const float*)d_in[4];
    const float* kv_a_ln_w= (const float*)d_in[5];
    const float* w_kc     = (const float*)d_in[6];
    const float* cos_sin  = (const float*)d_in[7];
    const float* k_cache_in  = (const float*)d_in[8];
    const float* rope_cache_in = (const float*)d_in[9];
    const int*   slot_map = (const int*)d_in[10];

    float* out   = (float*)d_out;
    float* q_out = out;                       // 4096*16*576
    float* k_out = out + 37748736;            // 4096*576
    float* kc_out = out + 40108032;           // 16384*512
    float* rc_out = out + 48496640;           // 16384*64

    char* ws = (char*)d_ws;
    // common region (live during GEMM1)
    bf16_t* hs_bf  = (bf16_t*)(ws + 0);            // 58,720,256 B
    bf16_t* wqkvaT = (bf16_t*)(ws + 58720256);     // 30,277,632 B
    bf16_t* wqbT   = (bf16_t*)(ws + 88997888);     //  9,437,184 B
    bf16_t* wkcT   = (bf16_t*)(ws + 98435072);     //  2,097,152 B
    float*  qkv0   = (float*)(ws + 100532224);     // 34,603,008 B

    // split-K=2 needs a second 34.6 MB partial at 135,135,232 (total 169,738,240 B)
    const bool splitk = ws_size >= (size_t)169738240;

    float*  qkv1;
    bf16_t* q_a;
    float*  q_b;
    bf16_t* q_nope;
    if (splitk) {
        qkv1   = (float*)(ws + 135135232);         // 34,603,008 B (dead after k_side)
        q_a    = (bf16_t*)(ws + 0);                // hs_bf region, dead after GEMM1
        q_b    = (float*)(ws + 12582912);          // 50,331,648 B, same region
        q_nope = (bf16_t*)(ws + 135135232);        // reuse qkv1 slot after k_side
    } else {
        qkv1   = nullptr;
        q_a    = (bf16_t*)(ws + 135135232);        // 12,582,912 B
        q_b    = (float*)(ws + 0);                 // hs_bf region, dead after GEMM1
        q_nope = (bf16_t*)(ws + 100532224);        // reuse qkv0 slot after k_side
    }

    // caches: full copy, then scatter-overwrite in k_side_kernel
    hipMemcpyAsync(kc_out, k_cache_in, (size_t)16384 * 512 * 4, hipMemcpyDeviceToDevice, stream);
    hipMemcpyAsync(rc_out, rope_cache_in, (size_t)16384 * 64 * 4, hipMemcpyDeviceToDevice, stream);

    cast_f32_bf16<<<2048, 256, 0, stream>>>(hs, hs_bf, (long)T_TOK * H_DIM / 8);
    transpose_cast<<<dim3(NQKV / 32, H_DIM / 32), 256, 0, stream>>>(w_qkv_a, wqkvaT, H_DIM, NQKV);
    transpose_cast<<<dim3(NQB / 32, QLORA / 32), 256, 0, stream>>>(w_q_b, wqbT, QLORA, NQB);
    transpose_cast<<<dim3(512 / 32, 2048 / 32), 256, 0, stream>>>(w_kc, wkcT, 2048, 512);

    // GEMM1: qkv = hs @ w_qkv_a   (4096 x 2112, K=7168)
    if (splitk) {
        gemm_mfma<<<dim3((NQKV + GBN - 1) / GBN, T_TOK / GBM, 2), 512, 0, stream>>>(
            hs_bf, H_DIM, 3584, wqkvaT, H_DIM, 3584,
            qkv0, NQKV, (long)T_TOK * NQKV, 3584, NQKV);
    } else {
        gemm_mfma<<<dim3((NQKV + GBN - 1) / GBN, T_TOK / GBM, 1), 512, 0, stream>>>(
            hs_bf, H_DIM, 0, wqkvaT, H_DIM, 0, qkv0, NQKV, 0, H_DIM, NQKV);
    }

    rms_q_kernel<<<T_TOK, 256, 0, stream>>>(qkv0, qkv1, q_a_ln_w, q_a);
    k_side_kernel<<<T_TOK, 256, 0, stream>>>(qkv0, qkv1, kv_a_ln_w, cos_sin, positions, slot_map,
                                             k_out, kc_out, rc_out);

    // GEMM2: q_b = q_a @ w_q_b   (4096 x 3072, K=1536)
    gemm_mfma<<<dim3(NQB / GBN, T_TOK / GBM, 1), 512, 0, stream>>>(
        q_a, QLORA, 0, wqbT, QLORA, 0, q_b, NQB, 0, QLORA, NQB);

    split_q_kernel<<<T_TOK, 256, 0, stream>>>(q_b, cos_sin, positions, q_nope, q_out);

    // GEMM3 (batched over heads): q_out[:, h, :512] = q_nope[h] @ w_kc[h]   (K=128, nt=2)
    gemm_mfma<<<dim3(KVLORA / GBN, T_TOK / GBM, NHEAD), 512, 0, stream>>>(
        q_nope, NOPE_D, (long)T_TOK * NOPE_D,
        wkcT, 2048, 128,
        q_out, NHEAD * 576, 576, NOPE_D, KVLORA);
}

// Round 8
// 373.607 us; speedup vs baseline: 1.0565x; 1.0565x over previous
//
#include <hip/hip_runtime.h>
#include <hip/hip_bf16.h>

typedef __bf16 bf16_t;
typedef __bf16 bf16x8 __attribute__((ext_vector_type(8)));
typedef float f32x4 __attribute__((ext_vector_type(4)));
typedef unsigned int uint;

#define T_TOK 4096
#define H_DIM 7168
#define QLORA 1536
#define KVLORA 512
#define ROPE_D 64
#define NOPE_D 128
#define NHEAD 16
#define NQKV 2112   /* QLORA + KVLORA + ROPE */
#define NQB  3072   /* NHEAD * 192 */
#define EPS_F 1e-6f

// ---------------- elementwise helpers ----------------

__global__ void cast_f32_bf16(const float* __restrict__ in, bf16_t* __restrict__ out, long n8)
{
    long stride = (long)gridDim.x * blockDim.x;
    for (long i = (long)blockIdx.x * blockDim.x + threadIdx.x; i < n8; i += stride) {
        const float4 a = ((const float4*)in)[i * 2];
        const float4 b = ((const float4*)in)[i * 2 + 1];
        bf16x8 v;
        v[0] = (bf16_t)a.x; v[1] = (bf16_t)a.y; v[2] = (bf16_t)a.z; v[3] = (bf16_t)a.w;
        v[4] = (bf16_t)b.x; v[5] = (bf16_t)b.y; v[6] = (bf16_t)b.z; v[7] = (bf16_t)b.w;
        ((bf16x8*)out)[i] = v;
    }
}

// out[C][R] (bf16) = transpose of in[R][C] (f32)
__global__ __launch_bounds__(256) void transpose_cast(const float* __restrict__ in,
                                                      bf16_t* __restrict__ out, int R, int C)
{
    __shared__ float tile[32][33];
    const int bx = blockIdx.x * 32;   // col block of in
    const int by = blockIdx.y * 32;   // row block of in
    const int tx = threadIdx.x & 31, ty = threadIdx.x >> 5;
    #pragma unroll
    for (int r = ty; r < 32; r += 8)
        tile[r][tx] = in[(long)(by + r) * C + bx + tx];
    __syncthreads();
    #pragma unroll
    for (int r = ty; r < 32; r += 8)
        out[(long)(bx + r) * R + by + tx] = (bf16_t)tile[tx][r];
}

// block reduction safe for repeated use (leading+trailing barriers)
__device__ inline float block_sum_256(float v)
{
    #pragma unroll
    for (int off = 32; off > 0; off >>= 1) v += __shfl_xor(v, off, 64);
    __shared__ float tmp[4];
    __syncthreads();
    if ((threadIdx.x & 63) == 0) tmp[threadIdx.x >> 6] = v;
    __syncthreads();
    return tmp[0] + tmp[1] + tmp[2] + tmp[3];
}

// fused: RMS-norm q-lora -> bf16 q_a;  RMS-norm latent + rope -> k_out/caches
__global__ __launch_bounds__(256) void rmsq_kside_kernel(
    const float* __restrict__ qkv, const float* __restrict__ qkvB,
    const float* __restrict__ q_w, const float* __restrict__ kv_w,
    const float* __restrict__ cos_sin, const int* __restrict__ positions,
    const int* __restrict__ slot_map,
    bf16_t* __restrict__ q_a, float* __restrict__ k_out,
    float* __restrict__ kc_out, float* __restrict__ rc_out)
{
    const int t = blockIdx.x;
    const float* x = qkv + (long)t * NQKV;
    const float* xB = qkvB ? qkvB + (long)t * NQKV : nullptr;

    // ---- q side: 1536 elems, 6/thread ----
    float loc[6];
    float ss = 0.f;
    #pragma unroll
    for (int i = 0; i < 6; i++) {
        int idx = threadIdx.x + 256 * i;
        float v = x[idx];
        if (xB) v += xB[idx];
        loc[i] = v; ss += v * v;
    }
    ss = block_sum_256(ss);
    const float scq = rsqrtf(ss / (float)QLORA + EPS_F);
    #pragma unroll
    for (int i = 0; i < 6; i++) {
        int idx = threadIdx.x + 256 * i;
        q_a[(long)t * QLORA + idx] = (bf16_t)(loc[i] * scq * q_w[idx]);
    }

    // ---- k side: latent 512 + rope 64 ----
    const float* lat = x + QLORA;
    const float* latB = xB ? xB + QLORA : nullptr;
    float v0 = lat[threadIdx.x];
    float v1 = lat[threadIdx.x + 256];
    if (latB) { v0 += latB[threadIdx.x]; v1 += latB[threadIdx.x + 256]; }
    float ssk = v0 * v0 + v1 * v1;
    ssk = block_sum_256(ssk);
    const float sck = rsqrtf(ssk / (float)KVLORA + EPS_F);
    const int slot = slot_map[t];
    const float a0 = v0 * sck * kv_w[threadIdx.x];
    const float a1 = v1 * sck * kv_w[threadIdx.x + 256];
    k_out[(long)t * 576 + threadIdx.x]        = a0;
    k_out[(long)t * 576 + 256 + threadIdx.x]  = a1;
    kc_out[(long)slot * KVLORA + threadIdx.x]       = a0;
    kc_out[(long)slot * KVLORA + 256 + threadIdx.x] = a1;
    if (threadIdx.x < 32) {
        const int j = threadIdx.x;
        const int pos = positions[t];
        const float c = cos_sin[pos * 64 + j];
        const float s = cos_sin[pos * 64 + 32 + j];
        float x1 = lat[KVLORA + 2 * j];
        float x2 = lat[KVLORA + 2 * j + 1];
        if (latB) { x1 += latB[KVLORA + 2 * j]; x2 += latB[KVLORA + 2 * j + 1]; }
        const float o1 = x1 * c - x2 * s;
        const float o2 = x2 * c + x1 * s;
        k_out[(long)t * 576 + 512 + j]      = o1;
        k_out[(long)t * 576 + 512 + 32 + j] = o2;
        rc_out[(long)slot * 64 + j]      = o1;
        rc_out[(long)slot * 64 + 32 + j] = o2;
    }
}

// ---------------- r5 GEMM: 2-phase dbuf bf16 MFMA, bank-swizzled LDS ----------
// C(MxN f32) = A(MxK bf16) * B^T(NxK bf16); M%128==0, K%64==0; N edge clamped.
// 128x128 tile, BK=64, 8 waves (2Mx4N, wave tile 64x32, 4x2 acc), gload_lds
// staging into 2-buf LDS; next tile staged BEFORE compute; one vmcnt(0)+barrier
// per K-step. Bank swizzle (rule #21, both sides): physical col byte c of row r
// at c ^ ((r&7)<<4); write side pre-swizzles the GLOBAL col chunk; read side
// XORs the frag base; ks=1 = base ^ 64.
#define GBM 128
#define GBN 128
#define GBK 64

__global__ __launch_bounds__(512) void gemm_mfma(
    const bf16_t* __restrict__ A, int lda, long sA,
    const bf16_t* __restrict__ Bt, int ldb, long sB,
    float* __restrict__ C, int ldc, long sC,
    int K, int N)
{
    __shared__ bf16_t As[2][GBM * GBK];   // 2 x 16 KB
    __shared__ bf16_t Bs[2][GBN * GBK];   // 2 x 16 KB

    const int nwg = gridDim.x * gridDim.y;
    const int bid = blockIdx.y * gridDim.x + blockIdx.x;
    const int cpx = nwg >> 3;
    const int swz = (bid & 7) * cpx + (bid >> 3);
    const int bx = swz % gridDim.x;
    const int by = swz / gridDim.x;

    const int tid = threadIdx.x;
    const int lane = tid & 63;
    const int w = tid >> 6;            // 0..7
    const int wr = w >> 2, wc = w & 3; // 2x4 wave grid; wave tile 64x32
    const int fr = lane & 15;
    const int kg = lane >> 4;

    const long brow = (long)by * GBM;
    const long bcol = (long)bx * GBN;

    const bf16_t* Ab = A + blockIdx.z * sA + brow * lda;
    const bf16_t* Bb = Bt + blockIdx.z * sB;
    float* Cb = C + blockIdx.z * sC + brow * ldc;

    const int srow = w * 16 + (lane >> 3);
    const int scol = (((lane & 7) ^ (lane >> 3)) * 8);

    const uint rd_sw = (uint)((kg * 16) ^ ((fr & 7) << 4));
    const uint a_base = (uint)(uintptr_t)(&As[0][0]) + (uint)((wr * 64 + fr) * 128) + rd_sw;
    const uint b_base = (uint)(uintptr_t)(&Bs[0][0]) + (uint)((wc * 32 + fr) * 128) + rd_sw;

    f32x4 acc[4][2] = {};

    const int nt = K / GBK;

    auto stage = [&](int buf, int k0) {
        #pragma unroll
        for (int it = 0; it < 2; it++) {
            const int r = srow + it * 8;
            __builtin_amdgcn_global_load_lds(
                (const __attribute__((address_space(1))) void*)(Ab + (long)r * lda + k0 + scol),
                (__attribute__((address_space(3))) void*)(&As[buf][(w * 16 + it * 8) * GBK]),
                16, 0, 0);
        }
        #pragma unroll
        for (int it = 0; it < 2; it++) {
            const int r = srow + it * 8;
            long bn = bcol + r; if (bn >= N) bn = N - 1;
            __builtin_amdgcn_global_load_lds(
                (const __attribute__((address_space(1))) void*)(Bb + bn * ldb + k0 + scol),
                (__attribute__((address_space(3))) void*)(&Bs[buf][(w * 16 + it * 8) * GBK]),
                16, 0, 0);
        }
    };

    stage(0, 0);
    asm volatile("s_waitcnt vmcnt(0)" ::: "memory");
    __builtin_amdgcn_s_barrier();

    int cur = 0;
    for (int t = 0; t < nt; ++t) {
        if (t + 1 < nt) stage(cur ^ 1, (t + 1) * GBK);

        const uint aa  = a_base + (uint)(cur * (GBM * GBK * 2));
        const uint bb  = b_base + (uint)(cur * (GBN * GBK * 2));
        const uint aaX = aa ^ 64u;
        const uint bbX = bb ^ 64u;
        bf16x8 a00, a01, a02, a03, a10, a11, a12, a13, b00, b01, b10, b11;
        asm volatile("ds_read_b128 %0, %1 offset:0"    : "=v"(a00) : "v"(aa));
        asm volatile("ds_read_b128 %0, %1 offset:2048" : "=v"(a01) : "v"(aa));
        asm volatile("ds_read_b128 %0, %1 offset:4096" : "=v"(a02) : "v"(aa));
        asm volatile("ds_read_b128 %0, %1 offset:6144" : "=v"(a03) : "v"(aa));
        asm volatile("ds_read_b128 %0, %1 offset:0"    : "=v"(a10) : "v"(aaX));
        asm volatile("ds_read_b128 %0, %1 offset:2048" : "=v"(a11) : "v"(aaX));
        asm volatile("ds_read_b128 %0, %1 offset:4096" : "=v"(a12) : "v"(aaX));
        asm volatile("ds_read_b128 %0, %1 offset:6144" : "=v"(a13) : "v"(aaX));
        asm volatile("ds_read_b128 %0, %1 offset:0"    : "=v"(b00) : "v"(bb));
        asm volatile("ds_read_b128 %0, %1 offset:2048" : "=v"(b01) : "v"(bb));
        asm volatile("ds_read_b128 %0, %1 offset:0"    : "=v"(b10) : "v"(bbX));
        asm volatile("ds_read_b128 %0, %1 offset:2048" : "=v"(b11) : "v"(bbX));
        asm volatile("s_waitcnt lgkmcnt(0)" ::: "memory");
        __builtin_amdgcn_sched_barrier(0);

        acc[0][0] = __builtin_amdgcn_mfma_f32_16x16x32_bf16(a00, b00, acc[0][0], 0, 0, 0);
        acc[0][1] = __builtin_amdgcn_mfma_f32_16x16x32_bf16(a00, b01, acc[0][1], 0, 0, 0);
        acc[1][0] = __builtin_amdgcn_mfma_f32_16x16x32_bf16(a01, b00, acc[1][0], 0, 0, 0);
        acc[1][1] = __builtin_amdgcn_mfma_f32_16x16x32_bf16(a01, b01, acc[1][1], 0, 0, 0);
        acc[2][0] = __builtin_amdgcn_mfma_f32_16x16x32_bf16(a02, b00, acc[2][0], 0, 0, 0);
        acc[2][1] = __builtin_amdgcn_mfma_f32_16x16x32_bf16(a02, b01, acc[2][1], 0, 0, 0);
        acc[3][0] = __builtin_amdgcn_mfma_f32_16x16x32_bf16(a03, b00, acc[3][0], 0, 0, 0);
        acc[3][1] = __builtin_amdgcn_mfma_f32_16x16x32_bf16(a03, b01, acc[3][1], 0, 0, 0);
        acc[0][0] = __builtin_amdgcn_mfma_f32_16x16x32_bf16(a10, b10, acc[0][0], 0, 0, 0);
        acc[0][1] = __builtin_amdgcn_mfma_f32_16x16x32_bf16(a10, b11, acc[0][1], 0, 0, 0);
        acc[1][0] = __builtin_amdgcn_mfma_f32_16x16x32_bf16(a11, b10, acc[1][0], 0, 0, 0);
        acc[1][1] = __builtin_amdgcn_mfma_f32_16x16x32_bf16(a11, b11, acc[1][1], 0, 0, 0);
        acc[2][0] = __builtin_amdgcn_mfma_f32_16x16x32_bf16(a12, b10, acc[2][0], 0, 0, 0);
        acc[2][1] = __builtin_amdgcn_mfma_f32_16x16x32_bf16(a12, b11, acc[2][1], 0, 0, 0);
        acc[3][0] = __builtin_amdgcn_mfma_f32_16x16x32_bf16(a13, b10, acc[3][0], 0, 0, 0);
        acc[3][1] = __builtin_amdgcn_mfma_f32_16x16x32_bf16(a13, b11, acc[3][1], 0, 0, 0);

        asm volatile("s_waitcnt vmcnt(0)" ::: "memory");
        __builtin_amdgcn_s_barrier();
        cur ^= 1;
    }

    #pragma unroll
    for (int i = 0; i < 4; i++) {
        #pragma unroll
        for (int j = 0; j < 2; j++) {
            const int row0 = wr * 64 + i * 16 + kg * 4;
            const long col = bcol + wc * 32 + j * 16 + fr;
            if (col < N) {
                #pragma unroll
                for (int r = 0; r < 4; r++)
                    Cb[(long)(row0 + r) * ldc + col] = acc[i][j][r];
            }
        }
    }
}

// ---------------- GEMM2 with fused split_q epilogue -------------------------
// q_b = q_a(4096x1536) @ wqbT^T -> per-frag epilogue:
//   col%192 < 128  -> q_nope[h][t][col%192] (bf16)
//   else           -> rope pair via shfl_xor(1) -> q_out[t][h][512+...]
// Region test is wave-uniform (frags 16-aligned; regions 64-aligned). Rope
// pairs are adjacent lanes (fr parity).
__global__ __launch_bounds__(512) void gemm2_fused(
    const bf16_t* __restrict__ A,   // q_a, lda=QLORA
    const bf16_t* __restrict__ Bt,  // wqbT, ldb=QLORA
    const float* __restrict__ cos_sin,
    const int* __restrict__ positions,
    bf16_t* __restrict__ q_nope,
    float* __restrict__ q_out)
{
    __shared__ bf16_t As[2][GBM * GBK];
    __shared__ bf16_t Bs[2][GBN * GBK];

    const int nwg = gridDim.x * gridDim.y;
    const int bid = blockIdx.y * gridDim.x + blockIdx.x;
    const int cpx = nwg >> 3;
    const int swz = (bid & 7) * cpx + (bid >> 3);
    const int bx = swz % gridDim.x;
    const int by = swz / gridDim.x;

    const int tid = threadIdx.x;
    const int lane = tid & 63;
    const int w = tid >> 6;
    const int wr = w >> 2, wc = w & 3;
    const int fr = lane & 15;
    const int kg = lane >> 4;

    const int brow = by * GBM;
    const int bcol = bx * GBN;

    const bf16_t* Ab = A + (long)brow * QLORA;
    const bf16_t* Bb = Bt + (long)bcol * QLORA;

    const int srow = w * 16 + (lane >> 3);
    const int scol = (((lane & 7) ^ (lane >> 3)) * 8);

    const uint rd_sw = (uint)((kg * 16) ^ ((fr & 7) << 4));
    const uint a_base = (uint)(uintptr_t)(&As[0][0]) + (uint)((wr * 64 + fr) * 128) + rd_sw;
    const uint b_base = (uint)(uintptr_t)(&Bs[0][0]) + (uint)((wc * 32 + fr) * 128) + rd_sw;

    f32x4 acc[4][2] = {};

    const int nt = QLORA / GBK;   // 24

    auto stage = [&](int buf, int k0) {
        #pragma unroll
        for (int it = 0; it < 2; it++) {
            const int r = srow + it * 8;
            __builtin_amdgcn_global_load_lds(
                (const __attribute__((address_space(1))) void*)(Ab + (long)r * QLORA + k0 + scol),
                (__attribute__((address_space(3))) void*)(&As[buf][(w * 16 + it * 8) * GBK]),
                16, 0, 0);
            __builtin_amdgcn_global_load_lds(
                (const __attribute__((address_space(1))) void*)(Bb + (long)r * QLORA + k0 + scol),
                (__attribute__((address_space(3))) void*)(&Bs[buf][(w * 16 + it * 8) * GBK]),
                16, 0, 0);
        }
    };

    stage(0, 0);
    asm volatile("s_waitcnt vmcnt(0)" ::: "memory");
    __builtin_amdgcn_s_barrier();

    int cur = 0;
    for (int t = 0; t < nt; ++t) {
        if (t + 1 < nt) stage(cur ^ 1, (t + 1) * GBK);

        const uint aa  = a_base + (uint)(cur * (GBM * GBK * 2));
        const uint bb  = b_base + (uint)(cur * (GBN * GBK * 2));
        const uint aaX = aa ^ 64u;
        const uint bbX = bb ^ 64u;
        bf16x8 a00, a01, a02, a03, a10, a11, a12, a13, b00, b01, b10, b11;
        asm volatile("ds_read_b128 %0, %1 offset:0"    : "=v"(a00) : "v"(aa));
        asm volatile("ds_read_b128 %0, %1 offset:2048" : "=v"(a01) : "v"(aa));
        asm volatile("ds_read_b128 %0, %1 offset:4096" : "=v"(a02) : "v"(aa));
        asm volatile("ds_read_b128 %0, %1 offset:6144" : "=v"(a03) : "v"(aa));
        asm volatile("ds_read_b128 %0, %1 offset:0"    : "=v"(a10) : "v"(aaX));
        asm volatile("ds_read_b128 %0, %1 offset:2048" : "=v"(a11) : "v"(aaX));
        asm volatile("ds_read_b128 %0, %1 offset:4096" : "=v"(a12) : "v"(aaX));
        asm volatile("ds_read_b128 %0, %1 offset:6144" : "=v"(a13) : "v"(aaX));
        asm volatile("ds_read_b128 %0, %1 offset:0"    : "=v"(b00) : "v"(bb));
        asm volatile("ds_read_b128 %0, %1 offset:2048" : "=v"(b01) : "v"(bb));
        asm volatile("ds_read_b128 %0, %1 offset:0"    : "=v"(b10) : "v"(bbX));
        asm volatile("ds_read_b128 %0, %1 offset:2048" : "=v"(b11) : "v"(bbX));
        asm volatile("s_waitcnt lgkmcnt(0)" ::: "memory");
        __builtin_amdgcn_sched_barrier(0);

        acc[0][0] = __builtin_amdgcn_mfma_f32_16x16x32_bf16(a00, b00, acc[0][0], 0, 0, 0);
        acc[0][1] = __builtin_amdgcn_mfma_f32_16x16x32_bf16(a00, b01, acc[0][1], 0, 0, 0);
        acc[1][0] = __builtin_amdgcn_mfma_f32_16x16x32_bf16(a01, b00, acc[1][0], 0, 0, 0);
        acc[1][1] = __builtin_amdgcn_mfma_f32_16x16x32_bf16(a01, b01, acc[1][1], 0, 0, 0);
        acc[2][0] = __builtin_amdgcn_mfma_f32_16x16x32_bf16(a02, b00, acc[2][0], 0, 0, 0);
        acc[2][1] = __builtin_amdgcn_mfma_f32_16x16x32_bf16(a02, b01, acc[2][1], 0, 0, 0);
        acc[3][0] = __builtin_amdgcn_mfma_f32_16x16x32_bf16(a03, b00, acc[3][0], 0, 0, 0);
        acc[3][1] = __builtin_amdgcn_mfma_f32_16x16x32_bf16(a03, b01, acc[3][1], 0, 0, 0);
        acc[0][0] = __builtin_amdgcn_mfma_f32_16x16x32_bf16(a10, b10, acc[0][0], 0, 0, 0);
        acc[0][1] = __builtin_amdgcn_mfma_f32_16x16x32_bf16(a10, b11, acc[0][1], 0, 0, 0);
        acc[1][0] = __builtin_amdgcn_mfma_f32_16x16x32_bf16(a11, b10, acc[1][0], 0, 0, 0);
        acc[1][1] = __builtin_amdgcn_mfma_f32_16x16x32_bf16(a11, b11, acc[1][1], 0, 0, 0);
        acc[2][0] = __builtin_amdgcn_mfma_f32_16x16x32_bf16(a12, b10, acc[2][0], 0, 0, 0);
        acc[2][1] = __builtin_amdgcn_mfma_f32_16x16x32_bf16(a12, b11, acc[2][1], 0, 0, 0);
        acc[3][0] = __builtin_amdgcn_mfma_f32_16x16x32_bf16(a13, b10, acc[3][0], 0, 0, 0);
        acc[3][1] = __builtin_amdgcn_mfma_f32_16x16x32_bf16(a13, b11, acc[3][1], 0, 0, 0);

        asm volatile("s_waitcnt vmcnt(0)" ::: "memory");
        __builtin_amdgcn_s_barrier();
        cur ^= 1;
    }

    // fused split_q epilogue
    #pragma unroll
    for (int i = 0; i < 4; i++) {
        #pragma unroll
        for (int j = 0; j < 2; j++) {
            const int row0 = wr * 64 + i * 16 + kg * 4;
            const int col  = bcol + wc * 32 + j * 16 + fr;
            const int h  = col / 192;
            const int jj = col - h * 192;
            if (jj < 128) {
                #pragma unroll
                for (int r = 0; r < 4; r++) {
                    const int t = brow + row0 + r;
                    q_nope[((long)h * T_TOK + t) * NOPE_D + jj] = (bf16_t)acc[i][j][r];
                }
            } else {
                const int idx = jj - 128;
                const int j2 = idx >> 1;
                const int odd = idx & 1;
                #pragma unroll
                for (int r = 0; r < 4; r++) {
                    const int t = brow + row0 + r;
                    const float v = acc[i][j][r];
                    const float p = __shfl_xor(v, 1, 64);
                    const int pos = positions[t];
                    const float c = cos_sin[pos * 64 + j2];
                    const float s = cos_sin[pos * 64 + 32 + j2];
                    const float o = odd ? (v * c + p * s) : (v * c - p * s);
                    q_out[(long)t * 9216 + h * 576 + 512 + (odd ? 32 : 0) + j2] = o;
                }
            }
        }
    }
}

// ---------------- launcher ----------------

extern "C" void kernel_launch(void* const* d_in, const int* in_sizes, int n_in,
                              void* d_out, int out_size, void* d_ws, size_t ws_size,
                              hipStream_t stream)
{
    const float* hs       = (const float*)d_in[0];
    const int*   positions= (const int*)d_in[1];
    const float* w_qkv_a  = (const float*)d_in[2];
    const float* q_a_ln_w = (const float*)d_in[3];
    const float* w_q_b    = (const float*)d_in[4];
    const float* kv_a_ln_w= (const float*)d_in[5];
    const float* w_kc     = (const float*)d_in[6];
    const float* cos_sin  = (const float*)d_in[7];
    const float* k_cache_in  = (const float*)d_in[8];
    const float* rope_cache_in = (const float*)d_in[9];
    const int*   slot_map = (const int*)d_in[10];

    float* out   = (float*)d_out;
    float* q_out = out;                       // 4096*16*576
    float* k_out = out + 37748736;            // 4096*576
    float* kc_out = out + 40108032;           // 16384*512
    float* rc_out = out + 48496640;           // 16384*64

    char* ws = (char*)d_ws;
    // common region (live during GEMM1)
    bf16_t* hs_bf  = (bf16_t*)(ws + 0);            // 58,720,256 B
    bf16_t* wqkvaT = (bf16_t*)(ws + 58720256);     // 30,277,632 B
    bf16_t* wqbT   = (bf16_t*)(ws + 88997888);     //  9,437,184 B
    bf16_t* wkcT   = (bf16_t*)(ws + 98435072);     //  2,097,152 B
    float*  qkv0   = (float*)(ws + 100532224);     // 34,603,008 B

    const bool splitk = ws_size >= (size_t)169738240;

    float*  qkv1;
    bf16_t* q_a;
    bf16_t* q_nope;
    if (splitk) {
        qkv1   = (float*)(ws + 135135232);         // 34,603,008 B (dead after rmsq_kside)
        q_a    = (bf16_t*)(ws + 0);                // hs_bf region, dead after GEMM1
        q_nope = (bf16_t*)(ws + 135135232);        // reuse qkv1 slot after rmsq_kside
    } else {
        qkv1   = nullptr;
        q_a    = (bf16_t*)(ws + 135135232);
        q_nope = (bf16_t*)(ws + 100532224);        // reuse qkv0 slot
    }

    // caches: full copy, then scatter-overwrite in rmsq_kside
    hipMemcpyAsync(kc_out, k_cache_in, (size_t)16384 * 512 * 4, hipMemcpyDeviceToDevice, stream);
    hipMemcpyAsync(rc_out, rope_cache_in, (size_t)16384 * 64 * 4, hipMemcpyDeviceToDevice, stream);

    cast_f32_bf16<<<2048, 256, 0, stream>>>(hs, hs_bf, (long)T_TOK * H_DIM / 8);
    transpose_cast<<<dim3(NQKV / 32, H_DIM / 32), 256, 0, stream>>>(w_qkv_a, wqkvaT, H_DIM, NQKV);
    transpose_cast<<<dim3(NQB / 32, QLORA / 32), 256, 0, stream>>>(w_q_b, wqbT, QLORA, NQB);
    transpose_cast<<<dim3(512 / 32, 2048 / 32), 256, 0, stream>>>(w_kc, wkcT, 2048, 512);

    // GEMM1: qkv = hs @ w_qkv_a   (4096 x 2112, K=7168)
    if (splitk) {
        gemm_mfma<<<dim3((NQKV + GBN - 1) / GBN, T_TOK / GBM, 2), 512, 0, stream>>>(
            hs_bf, H_DIM, 3584, wqkvaT, H_DIM, 3584,
            qkv0, NQKV, (long)T_TOK * NQKV, 3584, NQKV);
    } else {
        gemm_mfma<<<dim3((NQKV + GBN - 1) / GBN, T_TOK / GBM, 1), 512, 0, stream>>>(
            hs_bf, H_DIM, 0, wqkvaT, H_DIM, 0, qkv0, NQKV, 0, H_DIM, NQKV);
    }

    rmsq_kside_kernel<<<T_TOK, 256, 0, stream>>>(qkv0, qkv1, q_a_ln_w, kv_a_ln_w,
                                                 cos_sin, positions, slot_map,
                                                 q_a, k_out, kc_out, rc_out);

    // GEMM2 + fused split_q: writes q_nope (bf16) and q_out[..., 512:576]
    gemm2_fused<<<dim3(NQB / GBN, T_TOK / GBM), 512, 0, stream>>>(
        q_a, wqbT, cos_sin, positions, q_nope, q_out);

    // GEMM3 (batched over heads): q_out[:, h, :512] = q_nope[h] @ w_kc[h]   (K=128)
    gemm_mfma<<<dim3(KVLORA / GBN, T_TOK / GBM, NHEAD), 512, 0, stream>>>(
        q_nope, NOPE_D, (long)T_TOK * NOPE_D,
        wkcT, 2048, 128,
        q_out, NHEAD * 576, 576, NOPE_D, KVLORA);
}